// Round 1
// baseline (2869.133 us; speedup 1.0000x reference)
//
#include <hip/hip_runtime.h>

#define B_ 4
#define H_ 16
#define S_ 2048
#define D_ 64
#define SCALE_ 0.125f
#define TQ 64
#define TK 64
#define NT (S_ / TK)            // 32 k-tiles
#define LDW 72                  // f16 row stride in LDS (144 B, 16B-aligned)
#define OUT_W_OFF ((size_t)B_ * H_ * S_ * D_)   // 8388608 floats: O first, then weights

typedef _Float16 f16;
typedef __attribute__((ext_vector_type(2))) _Float16 f16x2;
typedef __attribute__((ext_vector_type(8))) _Float16 f16x8;
typedef __attribute__((ext_vector_type(16))) float   f32x16;

__global__ __launch_bounds__(256, 4)
void sdpa_fused_kernel(const float* __restrict__ Q, const float* __restrict__ K,
                       const float* __restrict__ V, const int* __restrict__ M,
                       float* __restrict__ out)
{
    __shared__ f16 Qs[TQ * LDW];
    __shared__ f16 Ks[TK * LDW];
    __shared__ f16 Ws[TQ * LDW];
    __shared__ float lpart[2][TQ];
    __shared__ float linv[TQ];

    const int tid = threadIdx.x;
    const int w   = tid >> 6;        // wave 0..3
    const int l   = tid & 63;        // lane
    const int lc  = l & 31;
    const int lh  = l >> 5;
    const int qt  = blockIdx.x >> 6; // 0..31
    const int bh  = blockIdx.x & 63; // 0..63  (b*16+h)
    const int b   = bh >> 4;
    const int q0  = qt * TQ;

    const float* Qp = Q + (size_t)bh * S_ * D_;
    const float* Kp = K + (size_t)bh * S_ * D_;
    const float* Vp = V + (size_t)bh * S_ * D_;
    const int*   Mp = M + (size_t)b * S_ * S_;
    float* Wout = out + OUT_W_OFF + (size_t)bh * S_ * S_;
    float* Op   = out + (size_t)bh * S_ * D_;

    const int mbase = (w >> 1) * 32;   // q-rows of this wave's quadrant
    const int nbase = (w & 1) * 32;    // cols (k or d) of this wave's quadrant

    // ---- stage Q tile fp32 -> f16 LDS (once) ----
    {
        const int r  = tid >> 4;          // 0..15
        const int c4 = (tid & 15) * 4;    // 0..60
        #pragma unroll
        for (int p = 0; p < 4; p++) {
            const int row = r + p * 16;
            const float4 v = *(const float4*)(Qp + (size_t)(q0 + row) * D_ + c4);
            f16x2 lo; lo[0] = (f16)v.x; lo[1] = (f16)v.y;
            f16x2 hi; hi[0] = (f16)v.z; hi[1] = (f16)v.w;
            *(f16x2*)(&Qs[row * LDW + c4])     = lo;
            *(f16x2*)(&Qs[row * LDW + c4 + 2]) = hi;
        }
    }

    // per-accumulator-register row index within the 32x32 quadrant
    int rowq[16];
    #pragma unroll
    for (int r = 0; r < 16; r++) rowq[r] = (r & 3) + 8 * (r >> 2) + 4 * lh;
    // precomputed global row offsets (rows are fixed across all k-tiles)
    int mro[16];   // row * S_   (mask + weights row offset)
    #pragma unroll
    for (int r = 0; r < 16; r++) mro[r] = (q0 + mbase + rowq[r]) * S_;

    float rsum[16];
    #pragma unroll
    for (int r = 0; r < 16; r++) rsum[r] = 0.f;

    __syncthreads();   // Qs ready

    // ================= phase 1: softmax denominators =================
    for (int t = 0; t < NT; t++) {
        const int k0 = t * TK;
        {   // stage K tile fp32 -> f16
            const int r  = tid >> 4;
            const int c4 = (tid & 15) * 4;
            #pragma unroll
            for (int p = 0; p < 4; p++) {
                const int row = r + p * 16;
                const float4 v = *(const float4*)(Kp + (size_t)(k0 + row) * D_ + c4);
                f16x2 lo; lo[0] = (f16)v.x; lo[1] = (f16)v.y;
                f16x2 hi; hi[0] = (f16)v.z; hi[1] = (f16)v.w;
                *(f16x2*)(&Ks[row * LDW + c4])     = lo;
                *(f16x2*)(&Ks[row * LDW + c4 + 2]) = hi;
            }
        }
        __syncthreads();   // Ks ready

        f32x16 acc;
        #pragma unroll
        for (int i = 0; i < 16; i++) acc[i] = 0.f;
        #pragma unroll
        for (int s = 0; s < 4; s++) {
            f16x8 af = *(const f16x8*)(&Qs[(mbase + lc) * LDW + lh * 8 + s * 16]);
            f16x8 bf = *(const f16x8*)(&Ks[(nbase + lc) * LDW + lh * 8 + s * 16]);
            acc = __builtin_amdgcn_mfma_f32_32x32x16_f16(af, bf, acc, 0, 0, 0);
        }

        const int kg = k0 + nbase + lc;
        #pragma unroll
        for (int r = 0; r < 16; r++) {
            const int m = Mp[(size_t)mro[r] + kg];
            const float s = acc[r] * SCALE_;
            rsum[r] += m ? __expf(s) : 0.f;
        }
        __syncthreads();   // before next iter overwrites Ks
    }

    // reduce row sums across the 32 columns held by this wave
    #pragma unroll
    for (int r = 0; r < 16; r++) {
        float v = rsum[r];
        v += __shfl_xor(v, 1, 64);
        v += __shfl_xor(v, 2, 64);
        v += __shfl_xor(v, 4, 64);
        v += __shfl_xor(v, 8, 64);
        v += __shfl_xor(v, 16, 64);
        if (lc == 0) lpart[w & 1][mbase + rowq[r]] = v;
    }
    __syncthreads();
    if (tid < TQ) linv[tid] = 1.0f / (lpart[0][tid] + lpart[1][tid]);
    __syncthreads();
    float invr[16];
    #pragma unroll
    for (int r = 0; r < 16; r++) invr[r] = linv[mbase + rowq[r]];

    f32x16 acco;
    #pragma unroll
    for (int i = 0; i < 16; i++) acco[i] = 0.f;

    // ================= phase 2: weights + O = W*V =================
    for (int t = 0; t < NT; t++) {
        const int k0 = t * TK;
        {   // stage K tile fp32 -> f16
            const int r  = tid >> 4;
            const int c4 = (tid & 15) * 4;
            #pragma unroll
            for (int p = 0; p < 4; p++) {
                const int row = r + p * 16;
                const float4 v = *(const float4*)(Kp + (size_t)(k0 + row) * D_ + c4);
                f16x2 lo; lo[0] = (f16)v.x; lo[1] = (f16)v.y;
                f16x2 hi; hi[0] = (f16)v.z; hi[1] = (f16)v.w;
                *(f16x2*)(&Ks[row * LDW + c4])     = lo;
                *(f16x2*)(&Ks[row * LDW + c4 + 2]) = hi;
            }
        }
        __syncthreads();   // S1: Ks ready (also: every wave is past prev-iter PV)

        f32x16 acc;
        #pragma unroll
        for (int i = 0; i < 16; i++) acc[i] = 0.f;
        #pragma unroll
        for (int s = 0; s < 4; s++) {
            f16x8 af = *(const f16x8*)(&Qs[(mbase + lc) * LDW + lh * 8 + s * 16]);
            f16x8 bf = *(const f16x8*)(&Ks[(nbase + lc) * LDW + lh * 8 + s * 16]);
            acc = __builtin_amdgcn_mfma_f32_32x32x16_f16(af, bf, acc, 0, 0, 0);
        }

        const int kg = k0 + nbase + lc;
        #pragma unroll
        for (int r = 0; r < 16; r++) {
            const int m = Mp[(size_t)mro[r] + kg];
            const float s = acc[r] * SCALE_;
            const float wgt = m ? __expf(s) * invr[r] : 0.f;
            __builtin_nontemporal_store(wgt, &Wout[(size_t)mro[r] + kg]);
            Ws[(mbase + rowq[r]) * LDW + nbase + lc] = (f16)wgt;
        }
        __syncthreads();   // S2: Ws (full 64x64 W tile) ready

        // O quadrant += W_tile * V_tile ; V B-fragments straight from global
        #pragma unroll
        for (int s = 0; s < 4; s++) {
            f16x8 af = *(const f16x8*)(&Ws[(mbase + lc) * LDW + lh * 8 + s * 16]);
            f16x8 bf;
            #pragma unroll
            for (int j = 0; j < 8; j++) {
                const int kk = k0 + lh * 8 + s * 16 + j;
                bf[j] = (f16)Vp[(size_t)kk * D_ + nbase + lc];
            }
            acco = __builtin_amdgcn_mfma_f32_32x32x16_f16(af, bf, acco, 0, 0, 0);
        }
        __syncthreads();   // S3: PV reads done; Ks/Ws reusable next iter
    }

    // ---- store O (already normalized: w included 1/l) ----
    #pragma unroll
    for (int r = 0; r < 16; r++) {
        const int rowg = q0 + mbase + rowq[r];
        __builtin_nontemporal_store(acco[r], &Op[(size_t)rowg * D_ + nbase + lc]);
    }
}

extern "C" void kernel_launch(void* const* d_in, const int* in_sizes, int n_in,
                              void* d_out, int out_size, void* d_ws, size_t ws_size,
                              hipStream_t stream) {
    const float* Q = (const float*)d_in[0];
    const float* K = (const float*)d_in[1];
    const float* V = (const float*)d_in[2];
    const int*   M = (const int*)d_in[3];
    float* out = (float*)d_out;
    (void)in_sizes; (void)n_in; (void)out_size; (void)d_ws; (void)ws_size;

    const int grid = (S_ / TQ) * B_ * H_;   // 32 q-tiles * 64 (b,h) = 2048 blocks
    sdpa_fused_kernel<<<dim3(grid), dim3(256), 0, stream>>>(Q, K, V, M, out);
}